// Round 1
// baseline (596.564 us; speedup 1.0000x reference)
//
#include <hip/hip_runtime.h>

// MSD: x[20000, 512, 3] fp32 -> msd[2000] fp32
// msd[td] = (1/(180*1536)) * sum_{i=0..179} sum_e (x[100i+td,e] - x[100i,e])^2
//
// Decomposition: 200 time-chunks of 100 frames. For chunk j, valid origins are
// exactly i in [j-19, j] (clipped to [0,179]) -> <=20 origin frames staged in LDS.
// Each moving frame is read from HBM exactly once (by its chunk's 3 slice-blocks).

#define NELEM     1536      // 512*3 floats per frame
#define E4_FRAME  384       // float4 per frame
#define TD_MAXC   2000
#define STRIDEC   100
#define NORIG     180       // number of time origins
#define CHUNK     100       // frames per chunk (== STRIDEC so window is exactly 20)
#define NCHUNK    200       // 20000 / 100
#define SLICES    3         // element slices per frame
#define E4_SLICE  128       // float4 per slice (512 floats)
#define WIN       20        // max origins per chunk window

__global__ __launch_bounds__(256)
void msd_accum_kernel(const float4* __restrict__ x, float* __restrict__ acc) {
    __shared__ float4 sOrig[WIN * E4_SLICE];   // 40 KB

    const int j   = blockIdx.x / SLICES;   // time chunk
    const int s   = blockIdx.x % SLICES;   // element slice
    const int tid = threadIdx.x;

    // origin window [iLo, iHi] for this chunk
    int iLo = j - (WIN - 1); if (iLo < 0) iLo = 0;
    int iHi = (j < NORIG - 1) ? j : (NORIG - 1);
    const int nOrig = iHi - iLo + 1;
    if (nOrig <= 0) return;                // chunk 199 has no valid origins

    const int e4base = s * E4_SLICE;

    // stage origin frames (this slice) into LDS, coalesced
    for (int f = tid; f < nOrig * E4_SLICE; f += 256) {
        const int io = f >> 7;                 // f / E4_SLICE
        const int e4 = f & (E4_SLICE - 1);
        sOrig[f] = x[(size_t)(iLo + io) * (STRIDEC * E4_FRAME) + e4base + e4];
    }
    __syncthreads();

    const int wave = tid >> 6;
    const int lane = tid & 63;

    // each wave owns frames r = wave, wave+4, ... within the chunk
    for (int r = wave; r < CHUNK; r += 4) {
        const int t = j * CHUNK + r;
        const size_t mb = (size_t)t * E4_FRAME + e4base;
        const float4 m0 = x[mb + lane];        // coalesced 1 KB per wave
        const float4 m1 = x[mb + lane + 64];

        for (int io = 0; io < nOrig; ++io) {
            const int i  = iLo + io;
            const int td = t - i * STRIDEC;    // guaranteed in [0, 2000)
            const float4 o0 = sOrig[io * E4_SLICE + lane];
            const float4 o1 = sOrig[io * E4_SLICE + lane + 64];

            float dx, dy, dz, dw, p;
            dx = m0.x - o0.x; dy = m0.y - o0.y; dz = m0.z - o0.z; dw = m0.w - o0.w;
            p  = dx*dx + dy*dy + dz*dz + dw*dw;
            dx = m1.x - o1.x; dy = m1.y - o1.y; dz = m1.z - o1.z; dw = m1.w - o1.w;
            p += dx*dx + dy*dy + dz*dz + dw*dw;

            // 64-lane butterfly reduce
            #pragma unroll
            for (int off = 32; off >= 1; off >>= 1)
                p += __shfl_xor(p, off, 64);

            if (lane == 0) atomicAdd(&acc[td], p);
        }
    }
}

__global__ void msd_finalize_kernel(float* __restrict__ out) {
    const int i = blockIdx.x * blockDim.x + threadIdx.x;
    if (i < TD_MAXC) out[i] *= (1.0f / ((float)NELEM * (float)NORIG));
}

extern "C" void kernel_launch(void* const* d_in, const int* in_sizes, int n_in,
                              void* d_out, int out_size, void* d_ws, size_t ws_size,
                              hipStream_t stream) {
    const float4* x = (const float4*)d_in[0];
    float* out = (float*)d_out;

    // d_out is poisoned 0xAA before every launch -> zero it, accumulate, scale.
    hipMemsetAsync(out, 0, TD_MAXC * sizeof(float), stream);
    msd_accum_kernel<<<NCHUNK * SLICES, 256, 0, stream>>>(x, out);
    msd_finalize_kernel<<<(TD_MAXC + 255) / 256, 256, 0, stream>>>(out);
}

// Round 2
// 239.801 us; speedup vs baseline: 2.4877x; 2.4877x over previous
//
#include <hip/hip_runtime.h>

// MSD: x[20000, 512, 3] fp32 -> msd[2000] fp32
// msd[td] = (1/(180*1536)) * sum_{i=0..179} sum_e (x[100i+td,e] - x[100i,e])^2
//
// Structure: block <-> (hundred-block c, element slice s). Frames t = 100c + r,
// r = tid < 100. Origin index i = c - io is BLOCK-UNIFORM (c from blockIdx,
// io unrolled) -> origin loads are wave-uniform (scalar-cache path / broadcast).
// Thread keeps acc[20] in registers (td = 100*io + r, bijective within block),
// flushes once per block with scale folded in. No LDS, no barriers, no shuffles.

#define ROW4      384    // float4 per frame (1536 floats)
#define NORIG     180
#define NC        199    // hundred-blocks with >=1 valid origin (c=199 has none)
#define SLICES    8
#define S4        48     // float4 per slice (192 floats)
#define KT        12     // k-tiles of 4 float4 per slice
#define WIN       20
#define SCALE     (1.0f / (1536.0f * 180.0f))

__global__ __launch_bounds__(128)
void msd_kernel(const float4* __restrict__ x4, float* __restrict__ out) {
    const int c = blockIdx.x / SLICES;     // hundred-block
    const int s = blockIdx.x % SLICES;     // element slice
    const int r = threadIdx.x;             // frame within hundred-block

    if (r >= 100) return;                  // 28 masked lanes in wave 1

    const int sbase = s * S4;              // float4 offset within a frame row
    const size_t mrow = (size_t)(100 * c + r) * ROW4 + sbase;

    // valid io range: i = c - io must be in [0, 180)
    const int io_lo = (c > NORIG - 1) ? (c - (NORIG - 1)) : 0;
    const int io_hi = (c < WIN - 1) ? c : (WIN - 1);

    float acc[WIN];
    #pragma unroll
    for (int io = 0; io < WIN; ++io) acc[io] = 0.0f;

    for (int kt = 0; kt < KT; ++kt) {
        const size_t mb = mrow + kt * 4;
        const float4 m0 = x4[mb + 0];
        const float4 m1 = x4[mb + 1];
        const float4 m2 = x4[mb + 2];
        const float4 m3 = x4[mb + 3];

        #pragma unroll
        for (int io = 0; io < WIN; ++io) {
            int i = c - io;                              // block-uniform
            i = (i < 0) ? 0 : ((i > NORIG - 1) ? NORIG - 1 : i);
            const float4* orow = x4 + (size_t)(i * 100) * ROW4 + sbase + kt * 4;
            const float4 o0 = orow[0];
            const float4 o1 = orow[1];
            const float4 o2 = orow[2];
            const float4 o3 = orow[3];

            float d, p;
            d = m0.x - o0.x; p  = d * d;
            d = m0.y - o0.y; p += d * d;
            d = m0.z - o0.z; p += d * d;
            d = m0.w - o0.w; p += d * d;
            d = m1.x - o1.x; p += d * d;
            d = m1.y - o1.y; p += d * d;
            d = m1.z - o1.z; p += d * d;
            d = m1.w - o1.w; p += d * d;
            d = m2.x - o2.x; p += d * d;
            d = m2.y - o2.y; p += d * d;
            d = m2.z - o2.z; p += d * d;
            d = m2.w - o2.w; p += d * d;
            d = m3.x - o3.x; p += d * d;
            d = m3.y - o3.y; p += d * d;
            d = m3.z - o3.z; p += d * d;
            d = m3.w - o3.w; p += d * d;
            acc[io] += p;
        }
    }

    // flush: td = 100*io + r, one predicated atomic per io (scale folded in)
    #pragma unroll
    for (int io = 0; io < WIN; ++io) {
        if (io >= io_lo && io <= io_hi)
            atomicAdd(&out[100 * io + r], acc[io] * SCALE);
    }
}

extern "C" void kernel_launch(void* const* d_in, const int* in_sizes, int n_in,
                              void* d_out, int out_size, void* d_ws, size_t ws_size,
                              hipStream_t stream) {
    const float4* x4 = (const float4*)d_in[0];
    float* out = (float*)d_out;

    hipMemsetAsync(out, 0, 2000 * sizeof(float), stream);
    msd_kernel<<<NC * SLICES, 128, 0, stream>>>(x4, out);
}